// Round 5
// baseline (5606.049 us; speedup 1.0000x reference)
//
#include <hip/hip_runtime.h>
#include <hip/hip_fp16.h>
#include <math.h>

#define Bsz 64
#define Tsz 1024
#define Isz 128
#define Hsz 512
#define KH  256   // H/2
#define Osz 10

// ---------------------------------------------------------------------------
// Register-tiled fp32 GEMM: C[M,N] = A[M,K] @ Bw[K,N] + bias[N]
// 64x128 block tile, 8x4 micro-tile, 256 threads.
// ---------------------------------------------------------------------------
__global__ __launch_bounds__(256) void gemm_bias_kernel(
    const float* __restrict__ A, const float* __restrict__ Bw,
    const float* __restrict__ bias, float* __restrict__ C,
    int M, int N, int K)
{
  __shared__ float As[32][68];   // [k][m], padded
  const int tid = threadIdx.x;
  const int m0 = blockIdx.x * 64;
  const int n0 = blockIdx.y * 128;
  const int ty = tid >> 5, tx = tid & 31;

  float acc[8][4] = {{0.f}};

  for (int kk = 0; kk < K; kk += 32) {
    __syncthreads();
#pragma unroll
    for (int i = tid; i < 64 * 32; i += 256) {
      int m = i >> 5, k = i & 31;
      As[k][m] = A[(size_t)(m0 + m) * K + kk + k];
    }
    __syncthreads();
#pragma unroll
    for (int k = 0; k < 32; ++k) {
      const float4 bv = *(const float4*)(&Bw[(size_t)(kk + k) * N + n0 + tx * 4]);
      float a[8];
#pragma unroll
      for (int i = 0; i < 8; ++i) a[i] = As[k][ty * 8 + i];
#pragma unroll
      for (int i = 0; i < 8; ++i) {
        acc[i][0] = fmaf(a[i], bv.x, acc[i][0]);
        acc[i][1] = fmaf(a[i], bv.y, acc[i][1]);
        acc[i][2] = fmaf(a[i], bv.z, acc[i][2]);
        acc[i][3] = fmaf(a[i], bv.w, acc[i][3]);
      }
    }
  }

  const float4 bb = *(const float4*)(&bias[n0 + tx * 4]);
#pragma unroll
  for (int i = 0; i < 8; ++i) {
    float4 v;
    v.x = acc[i][0] + bb.x; v.y = acc[i][1] + bb.y;
    v.z = acc[i][2] + bb.z; v.w = acc[i][3] + bb.w;
    *(float4*)(&C[(size_t)(m0 + ty * 8 + i) * N + n0 + tx * 4]) = v;
  }
}

// ---------------------------------------------------------------------------
// Wc = W_in @ W1a  (128x512 @ 512x256 -> 128x256), one block per row i.
// ---------------------------------------------------------------------------
__global__ __launch_bounds__(256) void wc_kernel(
    const float* __restrict__ W_in, const float* __restrict__ W1a,
    float* __restrict__ Wc)
{
  __shared__ float row[Hsz];
  const int i = blockIdx.x, c = threadIdx.x;
  for (int h = c; h < Hsz; h += 256) row[h] = W_in[(size_t)i * Hsz + h];
  __syncthreads();
  float acc = 0.f;
#pragma unroll 8
  for (int h = 0; h < Hsz; ++h)
    acc = fmaf(row[h], W1a[(size_t)h * KH + c], acc);
  Wc[(size_t)i * KH + c] = acc;
}

// b_U = b_in @ W1a + b_tau1  (256)
__global__ __launch_bounds__(256) void bu_kernel(
    const float* __restrict__ b_in, const float* __restrict__ W1a,
    const float* __restrict__ b_tau1, float* __restrict__ bU)
{
  const int c = threadIdx.x;
  float acc = b_tau1[c];
#pragma unroll 8
  for (int h = 0; h < Hsz; ++h)
    acc = fmaf(b_in[h], W1a[(size_t)h * KH + c], acc);
  bU[c] = acc;
}

// ---------------------------------------------------------------------------
// i8 dot4
// ---------------------------------------------------------------------------
__device__ __forceinline__ int dot4i8(int a, int b, int acc) {
#if __has_builtin(__builtin_amdgcn_sdot4)
  return __builtin_amdgcn_sdot4(a, b, acc, false);
#else
  acc += ((a << 24) >> 24) * ((b << 24) >> 24);
  acc += ((a << 16) >> 24) * ((b << 16) >> 24);
  acc += ((a << 8)  >> 24) * ((b << 8)  >> 24);
  acc += (a >> 24) * (b >> 24);
  return acc;
#endif
}

// ---------------------------------------------------------------------------
// Quantizer layouts: [G groups x C cols] i8; group g, dword di, byte e covers
// source k = 16g + 4di + e; flat dword index = g*(C*4)+c*4+di.
// ---------------------------------------------------------------------------

// drive: col j = output row of W_rec (512 cols, 32 groups over k=512)
__global__ __launch_bounds__(256) void drive_scale_kernel(
    const float* __restrict__ W_rec, float* __restrict__ CS0)
{
  const int j = blockIdx.x * 256 + threadIdx.x;  // 512
  float m = 0.f;
  for (int k = 0; k < Hsz; ++k)
    m = fmaxf(m, fabsf(W_rec[(size_t)j * Hsz + k]));
  CS0[j] = m;
}

__global__ __launch_bounds__(256) void drive_quant_kernel(
    const float* __restrict__ W_rec, const float* __restrict__ CS0,
    unsigned* __restrict__ Q0)
{
  int i = blockIdx.x * 256 + threadIdx.x;  // 65536 dwords
  if (i >= 32 * Hsz * 4) return;
  int di = i & 3, j = (i >> 2) & 511, g = i >> 11;
  int k0 = 16 * g + 4 * di;
  float ma = CS0[j];
  float r = (ma > 0.f) ? (127.f / ma) : 0.f;
  unsigned out = 0;
#pragma unroll
  for (int e = 0; e < 4; ++e) {
    int q = __float2int_rn(W_rec[(size_t)j * Hsz + k0 + e] * r);
    out |= ((unsigned)(q & 255)) << (8 * e);
  }
  Q0[i] = out;
}

// tau1: col c (256 cols), 32 groups over j=512 (source W1b[j][c])
__global__ __launch_bounds__(256) void tau1_scale_kernel(
    const float* __restrict__ W1b, float* __restrict__ CS1)
{
  const int c = threadIdx.x;  // 256
  float m = 0.f;
  for (int j = 0; j < Hsz; ++j)
    m = fmaxf(m, fabsf(W1b[(size_t)j * KH + c]));
  CS1[c] = m;
}

__global__ __launch_bounds__(256) void tau1_quant_kernel(
    const float* __restrict__ W1b, const float* __restrict__ CS1,
    unsigned* __restrict__ Q1)
{
  int i = blockIdx.x * 256 + threadIdx.x;  // 32768 dwords
  if (i >= 32 * KH * 4) return;
  int di = i & 3, c = (i >> 2) & 255, g = i >> 10;
  int j0 = 16 * g + 4 * di;
  float ma = CS1[c];
  float r = (ma > 0.f) ? (127.f / ma) : 0.f;
  unsigned out = 0;
#pragma unroll
  for (int e = 0; e < 4; ++e) {
    int q = __float2int_rn(W1b[(size_t)(j0 + e) * KH + c] * r);
    out |= ((unsigned)(q & 255)) << (8 * e);
  }
  Q1[i] = out;
}

// tau2: col j (512 cols), 16 groups over k=256 (source W_tau2[k][j])
__global__ __launch_bounds__(256) void tau2_scale_kernel(
    const float* __restrict__ W_tau2, float* __restrict__ CS2)
{
  const int j = blockIdx.x * 256 + threadIdx.x;  // 512
  float m = 0.f;
  for (int k = 0; k < KH; ++k)
    m = fmaxf(m, fabsf(W_tau2[(size_t)k * Hsz + j]));
  CS2[j] = m;
}

__global__ __launch_bounds__(256) void tau2_quant_kernel(
    const float* __restrict__ W_tau2, const float* __restrict__ CS2,
    unsigned* __restrict__ Q2)
{
  int i = blockIdx.x * 256 + threadIdx.x;  // 32768 dwords
  if (i >= 16 * Hsz * 4) return;
  int di = i & 3, j = (i >> 2) & 511, g = i >> 11;
  int k0 = 16 * g + 4 * di;
  float ma = CS2[j];
  float r = (ma > 0.f) ? (127.f / ma) : 0.f;
  unsigned out = 0;
#pragma unroll
  for (int e = 0; e < 4; ++e) {
    int q = __float2int_rn(W_tau2[(size_t)(k0 + e) * Hsz + j] * r);
    out |= ((unsigned)(q & 255)) << (8 * e);
  }
  Q2[i] = out;
}

// keep a loaded uint4 pinned in VGPRs
#define KEEP4(v) asm volatile("" : "+v"((v).x), "+v"((v).y), "+v"((v).z), "+v"((v).w))

// ---------------------------------------------------------------------------
// Sequential scan, R17 redesign: 1024 threads/WG (16 waves).
//
// Forensics R13-R16: the backend pins this kernel to the 128-VGPR tier no
// matter what launch bounds / attributes request (128,128,124,128 across 4
// variants), so a 512-thread design needing 168 persistent VGPRs always
// degenerates to re-streaming ~368 KB/step from L2 (~5400 cy/step, the
// measured 2.29 ms). Redesign so the demand FITS 128: at 1024 threads the
// per-thread weight share halves, and 128 VGPRs becomes the HARD cap
// (16 waves / 4 SIMDs = 4 waves/SIMD; 512-reg file / 4 = 128) -- demand
// and compiler target finally coincide.
//   tau1 : 4-way k-split (q=tid>>8), 8 cells/thread  -> 32 VGPR resident
//   drive: 2-way k-split (kh=tid>>9), 16 cells/thread -> 12 reg (48 VGPR)
//          + 3 streamed/step (48 KB/step, 13% of old stream) + 1 LDS
//   tau2 : all 16 groups in LDS (128 KB), k-split across kh
// Partials combine via LDS (parti[4][256], dpart/tpart[512]); 4 barriers.
// 16 waves/CU doubles latency hiding vs the old 8.
// ---------------------------------------------------------------------------
__global__ __launch_bounds__(1024) void scan_kernel(
    float* __restrict__ xps,           // in: xp [B,T,H]; out: hs [B,T,H]
    const float* __restrict__ U,       // [B,T,KH] (b_tau1 already added)
    const unsigned* __restrict__ Q0,   // i8 drive [32][512][4]
    const unsigned* __restrict__ Q1,   // i8 tau1  [32][256][4]
    const unsigned* __restrict__ Q2,   // i8 tau2  [16][512][4]
    const float* __restrict__ CS0,     // [512]
    const float* __restrict__ CS1,     // [256]
    const float* __restrict__ CS2,     // [512]
    const float* __restrict__ bias,    // [H]
    const float* __restrict__ b_tau2)  // [H]
{
  const int b   = blockIdx.x;
  const int tid = threadIdx.x;          // 0..1023
  const int kh  = tid >> 9;             // drive/tau2 k-half (0/1)
  const int j   = tid & 511;            // drive/tau2 column
  const int q   = (tid >> 8) & 3;       // tau1 k-quarter (0..3)
  const int c   = tid & 255;            // tau1 column

  extern __shared__ __align__(16) uint4 Wlds[];   // [0..8191]=tau2 g0..15;
                                                  // [8192..9215]=drive g15,g31
  __shared__ __align__(16) int Hq[2][128];        // i8 h, double-buffered
  __shared__ __align__(16) unsigned char Aq[KH];  // i8 A
  __shared__ float scaleA[4];                     // per-64-seg A amax
  __shared__ int   parti[4][KH];                  // tau1 partials
  __shared__ int   dpart[Hsz];                    // drive partial (kh=1)
  __shared__ float tpart[Hsz];                    // tau2 partial (kh=1)

  const float bias_r = bias[j];
  const float bt2_r  = b_tau2[j];
  const float cs0r = CS0[j] * (1.0f / 16129.0f);  // /127^2
  const float csr  = CS1[c] * (1.0f / 16129.0f);
  const float cs2r = CS2[j] * (1.0f / 16129.0f);
  float hold = 0.f;
  if (tid < 128) { Hq[0][tid] = 0; Hq[1][tid] = 0; }

  float* xprow = xps + (size_t)b * Tsz * Hsz;
  const float* Urow = U + (size_t)b * Tsz * KH;

  const uint4* __restrict__ Q0u4 = (const uint4*)Q0;
  const uint4* __restrict__ Q1u4 = (const uint4*)Q1;
  const uint4* __restrict__ Q2u4 = (const uint4*)Q2;
  const uint4* Aq4 = (const uint4*)Aq;
  const int kh16 = kh * 16, kh8 = kh * 8, kh2 = kh * 2, q8 = q * 8;

  // --- one-time LDS staging: tau2 g0..15 (128 KB) + drive g15/g31 (16 KB)
#pragma unroll
  for (int i = 0; i < 8; ++i)
    Wlds[i * 1024 + tid] = Q2u4[i * 1024 + tid];
  Wlds[8192 + tid] = Q0u4[(tid < 512) ? (15 * 512 + tid)
                                      : (31 * 512 + (tid - 512))];

  // --- one-time REGISTER staging ---
  uint4 w1r[8];    // tau1 groups q*8 .. q*8+7
#pragma unroll
  for (int gg = 0; gg < 8; ++gg)
    w1r[gg] = Q1u4[(size_t)(q8 + gg) * 256 + c];
  uint4 w0r[12];   // drive groups kh*16 .. kh*16+11
#pragma unroll
  for (int gg = 0; gg < 12; ++gg)
    w0r[gg] = Q0u4[(size_t)(kh16 + gg) * 512 + j];
#pragma unroll
  for (int gg = 0; gg < 8; ++gg) KEEP4(w1r[gg]);
#pragma unroll
  for (int gg = 0; gg < 12; ++gg) KEEP4(w0r[gg]);

  // streamed drive cells: groups kh*16+12..14
  const uint4* __restrict__ q0s = Q0u4 + (size_t)(kh16 + 12) * 512 + j;

  __syncthreads();

  // step-0 operands (subsequent steps prefetched inside the loop)
  float xpv = (kh == 0) ? xprow[j] : 0.f;
  float Uv  = (tid < KH) ? Urow[tid] : 0.f;

  for (int t = 0; t < Tsz; ++t) {
    const uint4* h4 = (const uint4*)Hq[t & 1];

    // streamed drive cells, issued early so L2 latency hides under P1/P2
    const uint4 sA = q0s[0];
    const uint4 sB = q0s[512];
    const uint4 sC = q0s[1024];

    // --- P1: tau1 partial (8 reg groups) ---
    int a = 0;
#pragma unroll
    for (int gg = 0; gg < 8; ++gg) {
      const uint4 w  = w1r[gg];
      const uint4 hv = h4[q8 + gg];
      a = dot4i8((int)w.x, (int)hv.x, a); a = dot4i8((int)w.y, (int)hv.y, a);
      a = dot4i8((int)w.z, (int)hv.z, a); a = dot4i8((int)w.w, (int)hv.w, a);
    }
    parti[q][c] = a;
    __syncthreads();                                   // bar1

    // --- P2: A + per-64-segment quantization (threads 0..255) ---
    if (tid < KH) {
      float aval = fmaxf(Uv + (float)(parti[0][tid] + parti[1][tid] +
                                      parti[2][tid] + parti[3][tid]) * csr, 0.f);
      float m = aval;
#pragma unroll
      for (int off = 32; off >= 1; off >>= 1)
        m = fmaxf(m, __shfl_xor(m, off));
      if ((tid & 63) == 0) scaleA[tid >> 6] = m;
      const float r = (m > 0.f) ? (127.f / m) : 0.f;
      Aq[tid] = (unsigned char)__float2int_rn(aval * r);
    }
    __syncthreads();                                   // bar2

    // prefetch next-step xp/U (last step reads past row -- mapped ws, junk ok)
    const float xpn = (kh == 0) ? xprow[Hsz + j] : 0.f;
    const float Un  = (tid < KH) ? Urow[KH + tid] : 0.f;
    const float sc0 = scaleA[kh2], sc1 = scaleA[kh2 + 1];

    // --- P3: drive partial (12 reg + 3 streamed + 1 LDS) + tau2 partial ---
    int d = 0;
#pragma unroll
    for (int gg = 0; gg < 12; ++gg) {
      const uint4 w  = w0r[gg];
      const uint4 hv = h4[kh16 + gg];
      d = dot4i8((int)w.x, (int)hv.x, d); d = dot4i8((int)w.y, (int)hv.y, d);
      d = dot4i8((int)w.z, (int)hv.z, d); d = dot4i8((int)w.w, (int)hv.w, d);
    }
    {
      const uint4 hv = h4[kh16 + 12];
      d = dot4i8((int)sA.x, (int)hv.x, d); d = dot4i8((int)sA.y, (int)hv.y, d);
      d = dot4i8((int)sA.z, (int)hv.z, d); d = dot4i8((int)sA.w, (int)hv.w, d);
    }
    {
      const uint4 hv = h4[kh16 + 13];
      d = dot4i8((int)sB.x, (int)hv.x, d); d = dot4i8((int)sB.y, (int)hv.y, d);
      d = dot4i8((int)sB.z, (int)hv.z, d); d = dot4i8((int)sB.w, (int)hv.w, d);
    }
    {
      const uint4 hv = h4[kh16 + 14];
      d = dot4i8((int)sC.x, (int)hv.x, d); d = dot4i8((int)sC.y, (int)hv.y, d);
      d = dot4i8((int)sC.z, (int)hv.z, d); d = dot4i8((int)sC.w, (int)hv.w, d);
    }
    {
      const uint4 w  = Wlds[8192 + tid];   // g15 (kh=0) / g31 (kh=1)
      const uint4 hv = h4[kh16 + 15];
      d = dot4i8((int)w.x, (int)hv.x, d); d = dot4i8((int)w.y, (int)hv.y, d);
      d = dot4i8((int)w.z, (int)hv.z, d); d = dot4i8((int)w.w, (int)hv.w, d);
    }

    int t2 = 0; float sp = 0.f;
#pragma unroll
    for (int gg = 0; gg < 8; ++gg) {
      const uint4 wt = Wlds[(kh8 + gg) * 512 + j];
      const uint4 av = Aq4[kh8 + gg];
      t2 = dot4i8((int)wt.x, (int)av.x, t2); t2 = dot4i8((int)wt.y, (int)av.y, t2);
      t2 = dot4i8((int)wt.z, (int)av.z, t2); t2 = dot4i8((int)wt.w, (int)av.w, t2);
      if ((gg & 3) == 3) {
        sp += (float)t2 * cs2r * ((gg < 4) ? sc0 : sc1);
        t2 = 0;
      }
    }
    if (kh) { dpart[j] = d; tpart[j] = sp; }
    __syncthreads();                                   // bar3

    // --- epilogue (kh==0 threads): combine partials, tau, tanh, Euler ---
    if (kh == 0) {
      const float s  = sp + tpart[j] + bt2_r;
      const float dd = xpv + bias_r + (float)(d + dpart[j]) * cs0r;
      const float tau = 5.0f + 45.0f / (1.0f + __expf(-s));
      const float e2 = __expf(2.0f * dd);
      const float drv = 1.0f - 2.0f / (e2 + 1.0f);     // tanh
      const float hnew = hold + (drv - hold) / tau;
      hold = hnew;
      ((char*)Hq[(t + 1) & 1])[j] = (char)(__float2int_rn(hnew * 127.f) & 255);
      xprow[j] = hnew;                                 // hs output
    }
    __syncthreads();                                   // bar4

    xpv = xpn; Uv = Un;
    xprow += Hsz;
    Urow  += KH;
  }
}

// ---------------------------------------------------------------------------
// Epilogue: out[m,o] = hs[m,:] @ W_out[:,o] + b_out[o].
// ---------------------------------------------------------------------------
__global__ __launch_bounds__(256) void outproj_kernel(
    const float* __restrict__ hs, const float* __restrict__ W_out,
    const float* __restrict__ b_out, float* __restrict__ out)
{
  __shared__ float hsL[16][516];       // 516 = 512+4: rows spread across banks
  __shared__ float WL[Hsz * Osz];      // 20 KB
  const int tid = threadIdx.x;
  const size_t m0 = (size_t)blockIdx.x * 16;

  for (int i = tid; i < Hsz * Osz; i += 256) WL[i] = W_out[i];

  const float4* src = (const float4*)(hs + m0 * Hsz);  // 2048 float4, contiguous
#pragma unroll
  for (int i = 0; i < 8; ++i) {
    int idx = i * 256 + tid;
    *(float4*)&hsL[idx >> 7][(idx & 127) * 4] = src[idx];
  }
  __syncthreads();

  const int r = tid >> 4, o = tid & 15;
  if (o < Osz) {
    float acc = b_out[o];
#pragma unroll 8
    for (int k4 = 0; k4 < 128; ++k4) {
      const float4 h4 = *(const float4*)&hsL[r][k4 * 4];
      acc = fmaf(h4.x, WL[(4 * k4 + 0) * Osz + o], acc);
      acc = fmaf(h4.y, WL[(4 * k4 + 1) * Osz + o], acc);
      acc = fmaf(h4.z, WL[(4 * k4 + 2) * Osz + o], acc);
      acc = fmaf(h4.w, WL[(4 * k4 + 3) * Osz + o], acc);
    }
    out[(m0 + r) * Osz + o] = acc;
  }
}

// ---------------------------------------------------------------------------
extern "C" void kernel_launch(void* const* d_in, const int* in_sizes, int n_in,
                              void* d_out, int out_size, void* d_ws, size_t ws_size,
                              hipStream_t stream) {
  (void)in_sizes; (void)n_in; (void)out_size; (void)ws_size;

  const float* x      = (const float*)d_in[0];
  const float* W_in   = (const float*)d_in[1];
  const float* b_in   = (const float*)d_in[2];
  const float* W_rec  = (const float*)d_in[3];
  const float* bias   = (const float*)d_in[4];
  const float* W_tau1 = (const float*)d_in[5];
  const float* b_tau1 = (const float*)d_in[6];
  const float* W_tau2 = (const float*)d_in[7];
  const float* b_tau2 = (const float*)d_in[8];
  const float* W_out  = (const float*)d_in[9];
  const float* b_out  = (const float*)d_in[10];
  float* out = (float*)d_out;

  char* ws = (char*)d_ws;
  size_t off = 0;
  float* xps = (float*)(ws + off); off += (size_t)Bsz * Tsz * Hsz * 4;  // 128 MiB
  float* U   = (float*)(ws + off); off += (size_t)Bsz * Tsz * KH * 4;   //  64 MiB
  unsigned* Q0 = (unsigned*)(ws + off); off += (size_t)32 * Hsz * 4 * 4;// 256 KiB
  unsigned* Q1 = (unsigned*)(ws + off); off += (size_t)32 * KH  * 4 * 4;// 128 KiB
  unsigned* Q2 = (unsigned*)(ws + off); off += (size_t)16 * Hsz * 4 * 4;// 128 KiB
  float* CS0   = (float*)(ws + off); off += 512 * 4;
  float* CS1   = (float*)(ws + off); off += 256 * 4;
  float* CS2   = (float*)(ws + off); off += 512 * 4;
  float* Wc    = (float*)(ws + off); off += (size_t)Isz * KH * 4;       // 128 KiB
  float* bU    = (float*)(ws + off); off += 256 * 4;

  const float* W1a = W_tau1;                     // rows 0..511
  const float* W1b = W_tau1 + (size_t)Hsz * KH;  // rows 512..1023

  const int M = Bsz * Tsz;  // 65536

  // opt-in to 144 KB dynamic LDS for the scan kernel
  (void)hipFuncSetAttribute((const void*)scan_kernel,
                            hipFuncAttributeMaxDynamicSharedMemorySize, 147456);

  // weight quantization + fused-U weight precompute (all small, independent)
  drive_scale_kernel<<<2, 256, 0, stream>>>(W_rec, CS0);
  drive_quant_kernel<<<256, 256, 0, stream>>>(W_rec, CS0, Q0);
  tau1_scale_kernel<<<1, 256, 0, stream>>>(W1b, CS1);
  tau1_quant_kernel<<<128, 256, 0, stream>>>(W1b, CS1, Q1);
  tau2_scale_kernel<<<2, 256, 0, stream>>>(W_tau2, CS2);
  tau2_quant_kernel<<<128, 256, 0, stream>>>(W_tau2, CS2, Q2);
  wc_kernel<<<Isz, 256, 0, stream>>>(W_in, W1a, Wc);
  bu_kernel<<<1, 256, 0, stream>>>(b_in, W1a, b_tau1, bU);

  // xp = x @ W_in + b_in            [65536,128]@[128,512]
  {
    dim3 grid(M / 64, Hsz / 128);
    gemm_bias_kernel<<<grid, 256, 0, stream>>>(x, W_in, b_in, xps, M, Hsz, Isz);
  }
  // U = x @ Wc + bU                 [65536,128]@[128,256]  (== xp@W1a + b_tau1)
  {
    dim3 grid(M / 64, KH / 128);
    gemm_bias_kernel<<<grid, 256, 0, stream>>>(x, Wc, bU, U, M, KH, Isz);
  }
  // scan (64 WGs, one per batch element; 1024 thr; 144 KB dynamic LDS)
  scan_kernel<<<Bsz, 1024, 147456, stream>>>(xps, U, Q0, Q1, Q2,
                                             CS0, CS1, CS2, bias, b_tau2);
  // output projection
  outproj_kernel<<<M / 16, 256, 0, stream>>>(xps, W_out, b_out, out);
}